// Round 4
// baseline (329.592 us; speedup 1.0000x reference)
//
#include <hip/hip_runtime.h>
#include <hip/hip_bf16.h>

// Problem constants (match reference)
constexpr int Bn = 16384;
constexpr int S  = 64;
constexpr int H  = 256;
constexpr int E  = 8;

constexpr int RPB  = 32;           // rows per combine block
constexpr int CBLK = Bn / RPB;     // 512 combine blocks
constexpr int TPB  = 512;          // 8 waves
constexpr int PSTR = H + 8;        // 264 bf16 row stride in LDS

typedef short bf16x8 __attribute__((ext_vector_type(8)));
typedef float f32x4  __attribute__((ext_vector_type(4)));

__device__ __forceinline__ float fast_tanh(float x) {
    const float ex = __expf(2.0f * x);
    return (ex - 1.0f) / (ex + 1.0f);
}

// ---------------------------------------------------------------------------
// Prep: Wt[e][d][h] (bf16) = We[e][h][d] (f32).  k(=h)-contiguous for MFMA
// B-frags. Grid: 32 blocks = 8 experts x 4 h-chunks of 64. 256 threads.
// Read side proven in round 3; write side now vectorized (bf16x8 stores).
// ---------------------------------------------------------------------------
__global__ __launch_bounds__(256) void prep_wt(const float* __restrict__ We,
                                               __hip_bfloat16* __restrict__ Wt) {
    __shared__ __hip_bfloat16 tile[64][H + 4];   // [h][d], stride 260 bf16
    const int e    = blockIdx.x >> 2;
    const int hblk = blockIdx.x & 3;
    const int t    = threadIdx.x;

    const float* src = We + ((size_t)e * H + hblk * 64) * H;   // 64 h-rows x 256 d
#pragma unroll
    for (int i = 0; i < 16; ++i) {
        const int idx = t + 256 * i;    // 0..4095
        const int hh  = idx >> 6;       // 0..63
        const int c4  = idx & 63;
        float4 v = reinterpret_cast<const float4*>(src + (size_t)hh * H)[c4];
        tile[hh][c4 * 4 + 0] = __float2bfloat16(v.x);
        tile[hh][c4 * 4 + 1] = __float2bfloat16(v.y);
        tile[hh][c4 * 4 + 2] = __float2bfloat16(v.z);
        tile[hh][c4 * 4 + 3] = __float2bfloat16(v.w);
    }
    __syncthreads();

    // write phase: 2048 octet-tasks (256 d x 8 h-octets), 16-B stores
#pragma unroll
    for (int i = 0; i < 8; ++i) {
        const int task = i * 256 + t;   // 0..2047
        const int d    = task >> 3;     // 0..255
        const int oct  = task & 7;      // 0..7 (h-octet within the 64 h)
        bf16x8 p;
#pragma unroll
        for (int u = 0; u < 8; ++u) {
            __hip_bfloat16 hv = tile[oct * 8 + u][d];
            p[u] = *reinterpret_cast<short*>(&hv);
        }
        *reinterpret_cast<bf16x8*>(
            Wt + ((size_t)e * H + d) * H + hblk * 64 + oct * 8) = p;
    }
}

// ---------------------------------------------------------------------------
// Pool: pure streaming mean over S. One row per block, 256 threads.
// Writes pooled bf16 [B][H] into workspace.
// ---------------------------------------------------------------------------
__global__ __launch_bounds__(256) void pool_kernel(const float* __restrict__ x,
                                                   __hip_bfloat16* __restrict__ pws) {
    const int b  = blockIdx.x;
    const int t  = threadIdx.x;
    const int c4 = t & 63;    // float4 column
    const int sg = t >> 6;    // s-group 0..3
    __shared__ float4 red4[4][64];

    const float4* xrow = reinterpret_cast<const float4*>(x + (size_t)b * (S * H));
    float4 acc = make_float4(0.f, 0.f, 0.f, 0.f);
#pragma unroll 4
    for (int i = 0; i < 16; ++i) {
        float4 v = xrow[(sg + 4 * i) * 64 + c4];
        acc.x += v.x; acc.y += v.y; acc.z += v.z; acc.w += v.w;
    }
    red4[sg][c4] = acc;
    __syncthreads();

    if (t < 64) {
        float4 p0 = red4[0][t], p1 = red4[1][t], p2 = red4[2][t], p3 = red4[3][t];
        const float sc = 1.0f / (float)S;
        float r[4];
        r[0] = (p0.x + p1.x + p2.x + p3.x) * sc;
        r[1] = (p0.y + p1.y + p2.y + p3.y) * sc;
        r[2] = (p0.z + p1.z + p2.z + p3.z) * sc;
        r[3] = (p0.w + p1.w + p2.w + p3.w) * sc;
        ushort4 pk;
        {
            __hip_bfloat16 h0 = __float2bfloat16(r[0]);
            __hip_bfloat16 h1 = __float2bfloat16(r[1]);
            __hip_bfloat16 h2 = __float2bfloat16(r[2]);
            __hip_bfloat16 h3 = __float2bfloat16(r[3]);
            pk.x = *reinterpret_cast<unsigned short*>(&h0);
            pk.y = *reinterpret_cast<unsigned short*>(&h1);
            pk.z = *reinterpret_cast<unsigned short*>(&h2);
            pk.w = *reinterpret_cast<unsigned short*>(&h3);
        }
        *reinterpret_cast<ushort4*>(pws + (size_t)b * H + t * 4) = pk;
    }
}

// ---------------------------------------------------------------------------
// Combine: stage pooled -> LDS, route (f64, identical to proven round-3 code),
// dense 8-expert MFMA + tanh + gate combine (verbatim round-3 phase 3).
// 512 blocks x 512 threads. Waves: rg = w>>2 (2 row-groups), dg = w&3.
// ---------------------------------------------------------------------------
__global__ __launch_bounds__(TPB, 4) void combine_kernel(
    const __hip_bfloat16* __restrict__ pws,    // [B][H] bf16
    const float* __restrict__ xr,              // [B][H]
    const float* __restrict__ Wr,              // [H][E]
    const float* __restrict__ be,              // [E][H]
    const __hip_bfloat16* __restrict__ Wt,     // [E][H d][H h] bf16
    float* __restrict__ out)                   // [B][H] f32
{
    const int b0 = blockIdx.x * RPB;
    const int t  = threadIdx.x;

    __shared__ __hip_bfloat16 pooled[RPB][PSTR];
    __shared__ float logit_s[RPB][E];
    __shared__ float gate_s[RPB][E];

    // ---- stage pooled rows (16 KB, coalesced bf16x8) ----
    {
        const __hip_bfloat16* src = pws + (size_t)b0 * H + t * 16;
#pragma unroll
        for (int u = 0; u < 2; ++u) {
            const int g = t * 16 + u * 8;           // element index 0..8191
            bf16x8 v = *reinterpret_cast<const bf16x8*>(src + u * 8);
            *reinterpret_cast<bf16x8*>(&pooled[g >> 8][g & 255]) = v;
        }
    }

    // ---- routing logits, f64 accumulation (identical to round-3) ----
    if (t < RPB * E) {
        const int r = t >> 3, e = t & 7;
        const float* xrp = xr + (size_t)(b0 + r) * H;
        double acc = 0.0;
#pragma unroll 8
        for (int h = 0; h < H; ++h)
            acc += (double)xrp[h] * (double)Wr[h * E + e];
        logit_s[r][e] = (float)acc;
    }
    __syncthreads();

    // ---- top-2 + softmax -> dense gate (identical to round-3) ----
    if (t < RPB) {
        int i0 = 0; float v0 = logit_s[t][0];
#pragma unroll
        for (int e = 1; e < E; ++e)
            if (logit_s[t][e] > v0) { v0 = logit_s[t][e]; i0 = e; }
        int i1 = -1; float v1 = -3.0e38f;
#pragma unroll
        for (int e = 0; e < E; ++e) {
            if (e == i0) continue;
            if (logit_s[t][e] > v1) { v1 = logit_s[t][e]; i1 = e; }
        }
        const float ex  = expf(v1 - v0);
        const float inv = 1.0f / (1.0f + ex);
#pragma unroll
        for (int e = 0; e < E; ++e) gate_s[t][e] = 0.f;
        gate_s[t][i0] = inv;
        gate_s[t][i1] = ex * inv;
    }
    __syncthreads();

    // ---- dense 8-expert MFMA + tanh + gate combine (verbatim round-3) ----
    {
        const int w  = t >> 6;
        const int l  = t & 63;
        const int rg = w >> 2;          // row-group: rows rg*16 .. +15
        const int dg = w & 3;           // d-group:  cols dg*64 .. +63
        const int lr = l & 15;
        const int lq = l >> 4;          // quarter 0..3

        f32x4 oacc[4];
#pragma unroll
        for (int n = 0; n < 4; ++n) oacc[n] = 0.f;

        const __hip_bfloat16* abase = &pooled[rg * 16 + lr][lq * 8];

        for (int e = 0; e < E; ++e) {
            f32x4 acc[4];
#pragma unroll
            for (int n = 0; n < 4; ++n) acc[n] = 0.f;

            const __hip_bfloat16* wb =
                Wt + ((size_t)e * H + dg * 64 + lr) * H + lq * 8;

#pragma unroll
            for (int kk = 0; kk < 8; ++kk) {
                const bf16x8 a = *reinterpret_cast<const bf16x8*>(abase + kk * 32);
                bf16x8 bfr[4];
#pragma unroll
                for (int n = 0; n < 4; ++n)
                    bfr[n] = *reinterpret_cast<const bf16x8*>(wb + (size_t)n * 16 * H + kk * 32);
#pragma unroll
                for (int n = 0; n < 4; ++n)
                    acc[n] = __builtin_amdgcn_mfma_f32_16x16x32_bf16(a, bfr[n], acc[n], 0, 0, 0);
            }

            float g[4];
#pragma unroll
            for (int j = 0; j < 4; ++j) g[j] = gate_s[rg * 16 + lq * 4 + j][e];
#pragma unroll
            for (int n = 0; n < 4; ++n) {
                const int d = dg * 64 + n * 16 + lr;
                const float bias = be[e * H + d];
#pragma unroll
                for (int j = 0; j < 4; ++j)
                    oacc[n][j] += g[j] * fast_tanh(acc[n][j] + bias);
            }
        }

#pragma unroll
        for (int n = 0; n < 4; ++n) {
            const int d = dg * 64 + n * 16 + lr;
#pragma unroll
            for (int j = 0; j < 4; ++j) {
                const int r = rg * 16 + lq * 4 + j;
                out[(size_t)(b0 + r) * H + d] = oacc[n][j];
            }
        }
    }
}

// ---------------------------------------------------------------------------
// Fallback (round-2 kernel, proven correct) if ws is too small.
// ---------------------------------------------------------------------------
__global__ __launch_bounds__(256) void moe_fused_fallback(
    const float* __restrict__ x, const float* __restrict__ xr,
    const float* __restrict__ Wr, const float* __restrict__ We,
    const float* __restrict__ be, float* __restrict__ out)
{
    const int b = blockIdx.x;
    const int t = threadIdx.x;

    __shared__ float  pooled[H];
    __shared__ float  xr_s[H];
    __shared__ float4 red4[4][64];
    __shared__ float  logits_s[E];
    __shared__ int    sel[2];
    __shared__ float  wsel[2];

    {
        const float4* xrow = reinterpret_cast<const float4*>(x + (size_t)b * S * H);
        const int c4 = t & 63;
        const int sg = t >> 6;
        float4 acc = make_float4(0.f, 0.f, 0.f, 0.f);
#pragma unroll
        for (int i = 0; i < 16; ++i) {
            float4 v = xrow[(sg + 4 * i) * 64 + c4];
            acc.x += v.x; acc.y += v.y; acc.z += v.z; acc.w += v.w;
        }
        red4[sg][c4] = acc;
        xr_s[t] = xr[(size_t)b * H + t];
    }
    __syncthreads();
    {
        const float* r0 = reinterpret_cast<const float*>(&red4[0][0]);
        const float* r1 = reinterpret_cast<const float*>(&red4[1][0]);
        const float* r2 = reinterpret_cast<const float*>(&red4[2][0]);
        const float* r3 = reinterpret_cast<const float*>(&red4[3][0]);
        pooled[t] = (r0[t] + r1[t] + r2[t] + r3[t]) * (1.0f / (float)S);
    }
    if (t < E) {
        double acc = 0.0;
        for (int h = 0; h < H; ++h)
            acc += (double)xr_s[h] * (double)Wr[h * E + t];
        logits_s[t] = (float)acc;
    }
    __syncthreads();
    if (t == 0) {
        int i0 = 0; float v0 = logits_s[0];
        for (int e = 1; e < E; ++e)
            if (logits_s[e] > v0) { v0 = logits_s[e]; i0 = e; }
        int i1 = -1; float v1 = -3.0e38f;
        for (int e = 0; e < E; ++e) {
            if (e == i0) continue;
            if (logits_s[e] > v1) { v1 = logits_s[e]; i1 = e; }
        }
        const float ex = expf(v1 - v0);
        const float inv = 1.0f / (1.0f + ex);
        sel[0] = i0; sel[1] = i1;
        wsel[0] = inv; wsel[1] = ex * inv;
    }
    __syncthreads();
    {
        const int   e0 = sel[0], e1 = sel[1];
        const float w0 = wsel[0], w1 = wsel[1];
        const float* W0 = We + (size_t)e0 * H * H + t;
        const float* W1 = We + (size_t)e1 * H * H + t;
        float a0 = be[e0 * H + t];
        float a1 = be[e1 * H + t];
#pragma unroll 8
        for (int h = 0; h < H; ++h) {
            const float p = pooled[h];
            a0 = fmaf(p, W0[(size_t)h * H], a0);
            a1 = fmaf(p, W1[(size_t)h * H], a1);
        }
        out[(size_t)b * H + t] = w0 * tanhf(a0) + w1 * tanhf(a1);
    }
}

extern "C" void kernel_launch(void* const* d_in, const int* in_sizes, int n_in,
                              void* d_out, int out_size, void* d_ws, size_t ws_size,
                              hipStream_t stream) {
    const float* x  = (const float*)d_in[0];   // [B,S,H]
    const float* xr = (const float*)d_in[1];   // [B,H]
    const float* Wr = (const float*)d_in[2];   // [H,E]
    const float* We = (const float*)d_in[3];   // [E,H,H]
    const float* be = (const float*)d_in[4];   // [E,H]
    float* out = (float*)d_out;

    (void)in_sizes; (void)n_in; (void)out_size;

    const size_t wt_elems = (size_t)E * H * H;                    // 524288
    const size_t need = (wt_elems + (size_t)Bn * H) * sizeof(__hip_bfloat16); // 9 MiB
    if (ws_size >= need) {
        __hip_bfloat16* Wt  = (__hip_bfloat16*)d_ws;
        __hip_bfloat16* pws = Wt + wt_elems;
        prep_wt<<<32, 256, 0, stream>>>(We, Wt);
        pool_kernel<<<Bn, 256, 0, stream>>>(x, pws);
        combine_kernel<<<CBLK, TPB, 0, stream>>>(pws, xr, Wr, be, Wt, out);
    } else {
        moe_fused_fallback<<<Bn, 256, 0, stream>>>(x, xr, Wr, We, be, out);
    }
}

// Round 5
// 275.661 us; speedup vs baseline: 1.1956x; 1.1956x over previous
//
#include <hip/hip_runtime.h>
#include <hip/hip_bf16.h>

// Problem constants (match reference)
constexpr int Bn = 16384;
constexpr int S  = 64;
constexpr int H  = 256;
constexpr int E  = 8;

constexpr int RPB  = 32;           // rows per combine block
constexpr int CBLK = Bn / RPB;     // 512 combine blocks
constexpr int TPB  = 512;          // 8 waves
constexpr int PSTR = H + 8;        // 264 bf16 row stride in LDS

typedef short bf16x8 __attribute__((ext_vector_type(8)));
typedef float f32x4  __attribute__((ext_vector_type(4)));

__device__ __forceinline__ float fast_tanh(float x) {
    const float ex = __expf(2.0f * x);
    return (ex - 1.0f) / (ex + 1.0f);
}

// ---------------------------------------------------------------------------
// Prep: We [E][H][H] f32 -> Wf in MFMA-fragment order (bf16).
// Chunk c = ((e*8 + kk)*16 + nt)*64 + lane holds 8 bf16; element j is
//   We[e][h = kk*32 + (lane>>4)*8 + j][d = nt*16 + (lane&15)]
// so combine's B-frag load is base + lane*16B -> fully coalesced.
// Grid: 32 blocks = 8 experts x 4 h-chunks of 64. 256 threads.
// ---------------------------------------------------------------------------
__global__ __launch_bounds__(256) void prep_wfrag(const float* __restrict__ We,
                                                  __hip_bfloat16* __restrict__ Wf) {
    __shared__ __hip_bfloat16 tile[64][H + 4];   // [h_local][d], stride 260 bf16
    const int e    = blockIdx.x >> 2;
    const int hblk = blockIdx.x & 3;
    const int t    = threadIdx.x;

    const float* src = We + ((size_t)e * H + hblk * 64) * H;   // 64 h-rows x 256 d
#pragma unroll
    for (int i = 0; i < 16; ++i) {
        const int idx = t + 256 * i;    // 0..4095
        const int hh  = idx >> 6;       // 0..63
        const int c4  = idx & 63;
        float4 v = reinterpret_cast<const float4*>(src + (size_t)hh * H)[c4];
        tile[hh][c4 * 4 + 0] = __float2bfloat16(v.x);
        tile[hh][c4 * 4 + 1] = __float2bfloat16(v.y);
        tile[hh][c4 * 4 + 2] = __float2bfloat16(v.z);
        tile[hh][c4 * 4 + 3] = __float2bfloat16(v.w);
    }
    __syncthreads();

    // write phase: 2048 16B-chunks (kk2 x nt x lane), coalesced dwordx4 stores
#pragma unroll
    for (int i = 0; i < 8; ++i) {
        const int task = i * 256 + t;     // 0..2047
        const int kk2  = task >> 10;      // 0..1  (k-tile within this h-chunk)
        const int nt   = (task >> 6) & 15;
        const int l    = task & 63;
        const int kk   = hblk * 2 + kk2;  // global k-tile 0..7
        const int hlb  = kk2 * 32 + (l >> 4) * 8;   // h_local base
        const int d    = nt * 16 + (l & 15);
        bf16x8 p;
#pragma unroll
        for (int j = 0; j < 8; ++j) {
            __hip_bfloat16 hv = tile[hlb + j][d];
            p[j] = *reinterpret_cast<short*>(&hv);
        }
        reinterpret_cast<bf16x8*>(Wf)[(((size_t)(e * 8 + kk) * 16 + nt) * 64 + l)] = p;
    }
}

// ---------------------------------------------------------------------------
// Pool: pure stream, one WAVE per row, no LDS, no reduction.
// lane = float4 column; each lane accumulates all S=64 samples of its column
// (4 chains for ILP), writes 4 bf16 (8B, coalesced).
// Grid: 4096 blocks x 256 threads (4 rows/block).
// ---------------------------------------------------------------------------
__global__ __launch_bounds__(256) void pool_kernel(const float* __restrict__ x,
                                                   __hip_bfloat16* __restrict__ pws) {
    const int t   = threadIdx.x;
    const int row = blockIdx.x * 4 + (t >> 6);
    const int c4  = t & 63;

    const float4* xrow = reinterpret_cast<const float4*>(x + (size_t)row * (S * H));
    float4 a0 = make_float4(0.f,0.f,0.f,0.f), a1 = a0, a2 = a0, a3 = a0;
#pragma unroll 16
    for (int s = 0; s < S; s += 4) {
        float4 v0 = xrow[(s + 0) * 64 + c4];
        float4 v1 = xrow[(s + 1) * 64 + c4];
        float4 v2 = xrow[(s + 2) * 64 + c4];
        float4 v3 = xrow[(s + 3) * 64 + c4];
        a0.x += v0.x; a0.y += v0.y; a0.z += v0.z; a0.w += v0.w;
        a1.x += v1.x; a1.y += v1.y; a1.z += v1.z; a1.w += v1.w;
        a2.x += v2.x; a2.y += v2.y; a2.z += v2.z; a2.w += v2.w;
        a3.x += v3.x; a3.y += v3.y; a3.z += v3.z; a3.w += v3.w;
    }
    const float sc = 1.0f / (float)S;
    float r0 = (a0.x + a1.x) + (a2.x + a3.x);
    float r1 = (a0.y + a1.y) + (a2.y + a3.y);
    float r2 = (a0.z + a1.z) + (a2.z + a3.z);
    float r3 = (a0.w + a1.w) + (a2.w + a3.w);
    ushort4 pk;
    {
        __hip_bfloat16 h0 = __float2bfloat16(r0 * sc);
        __hip_bfloat16 h1 = __float2bfloat16(r1 * sc);
        __hip_bfloat16 h2 = __float2bfloat16(r2 * sc);
        __hip_bfloat16 h3 = __float2bfloat16(r3 * sc);
        pk.x = *reinterpret_cast<unsigned short*>(&h0);
        pk.y = *reinterpret_cast<unsigned short*>(&h1);
        pk.z = *reinterpret_cast<unsigned short*>(&h2);
        pk.w = *reinterpret_cast<unsigned short*>(&h3);
    }
    *reinterpret_cast<ushort4*>(pws + (size_t)row * H + c4 * 4) = pk;
}

// ---------------------------------------------------------------------------
// Combine: stage pooled -> LDS, route (f64, proven), dense 8-expert MFMA with
// fragment-ordered Wf (coalesced B loads), tanh, gate combine.
// 512 blocks x 512 threads. Waves: rg = w>>2, dg = w&3.
// ---------------------------------------------------------------------------
__global__ __launch_bounds__(TPB, 4) void combine_kernel(
    const __hip_bfloat16* __restrict__ pws,    // [B][H] bf16
    const float* __restrict__ xr,              // [B][H]
    const float* __restrict__ Wr,              // [H][E]
    const float* __restrict__ be,              // [E][H]
    const __hip_bfloat16* __restrict__ Wf,     // fragment-ordered, 1 MiB
    float* __restrict__ out)                   // [B][H] f32
{
    const int b0 = blockIdx.x * RPB;
    const int t  = threadIdx.x;

    __shared__ __hip_bfloat16 pooled[RPB][PSTR];
    __shared__ float logit_s[RPB][E];
    __shared__ float gate_s[RPB][E];

    // ---- stage pooled rows (16 KB, coalesced bf16x8) ----
    {
        const __hip_bfloat16* src = pws + (size_t)b0 * H + t * 16;
#pragma unroll
        for (int u = 0; u < 2; ++u) {
            const int g = t * 16 + u * 8;           // element index 0..8191
            bf16x8 v = *reinterpret_cast<const bf16x8*>(src + u * 8);
            *reinterpret_cast<bf16x8*>(&pooled[g >> 8][g & 255]) = v;
        }
    }

    // ---- routing logits, f64 accumulation (proven) ----
    if (t < RPB * E) {
        const int r = t >> 3, e = t & 7;
        const float* xrp = xr + (size_t)(b0 + r) * H;
        double acc = 0.0;
#pragma unroll 8
        for (int h = 0; h < H; ++h)
            acc += (double)xrp[h] * (double)Wr[h * E + e];
        logit_s[r][e] = (float)acc;
    }
    __syncthreads();

    // ---- top-2 + softmax -> dense gate (proven) ----
    if (t < RPB) {
        int i0 = 0; float v0 = logit_s[t][0];
#pragma unroll
        for (int e = 1; e < E; ++e)
            if (logit_s[t][e] > v0) { v0 = logit_s[t][e]; i0 = e; }
        int i1 = -1; float v1 = -3.0e38f;
#pragma unroll
        for (int e = 0; e < E; ++e) {
            if (e == i0) continue;
            if (logit_s[t][e] > v1) { v1 = logit_s[t][e]; i1 = e; }
        }
        const float ex  = expf(v1 - v0);
        const float inv = 1.0f / (1.0f + ex);
#pragma unroll
        for (int e = 0; e < E; ++e) gate_s[t][e] = 0.f;
        gate_s[t][i0] = inv;
        gate_s[t][i1] = ex * inv;
    }
    __syncthreads();

    // ---- dense 8-expert MFMA + tanh + gate combine ----
    {
        const int w  = t >> 6;
        const int l  = t & 63;
        const int rg = w >> 2;          // row-group: rows rg*16 .. +15
        const int dg = w & 3;           // d-group:  cols dg*64 .. +63
        const int lr = l & 15;
        const int lq = l >> 4;          // quarter 0..3

        f32x4 oacc[4];
#pragma unroll
        for (int n = 0; n < 4; ++n) oacc[n] = 0.f;

        const __hip_bfloat16* abase = &pooled[rg * 16 + lr][lq * 8];
        const bf16x8* wf8 = reinterpret_cast<const bf16x8*>(Wf);

        for (int e = 0; e < E; ++e) {
            f32x4 acc[4];
#pragma unroll
            for (int n = 0; n < 4; ++n) acc[n] = 0.f;

#pragma unroll
            for (int kk = 0; kk < 8; ++kk) {
                const bf16x8 a = *reinterpret_cast<const bf16x8*>(abase + kk * 32);
                // coalesced: chunk ((e*8+kk)*16 + dg*4 + n)*64 + l
                const size_t kb = ((size_t)(e * 8 + kk) * 16 + dg * 4) * 64 + l;
                bf16x8 bfr[4];
#pragma unroll
                for (int n = 0; n < 4; ++n)
                    bfr[n] = wf8[kb + (size_t)n * 64];
#pragma unroll
                for (int n = 0; n < 4; ++n)
                    acc[n] = __builtin_amdgcn_mfma_f32_16x16x32_bf16(a, bfr[n], acc[n], 0, 0, 0);
            }

            float g[4];
#pragma unroll
            for (int j = 0; j < 4; ++j) g[j] = gate_s[rg * 16 + lq * 4 + j][e];
#pragma unroll
            for (int n = 0; n < 4; ++n) {
                const int d = dg * 64 + n * 16 + lr;
                const float bias = be[e * H + d];
#pragma unroll
                for (int j = 0; j < 4; ++j)
                    oacc[n][j] += g[j] * fast_tanh(acc[n][j] + bias);
            }
        }

        // C/D layout: col = lane&15 (-> d), row = (lane>>4)*4 + j (-> batch row)
#pragma unroll
        for (int n = 0; n < 4; ++n) {
            const int d = dg * 64 + n * 16 + lr;
#pragma unroll
            for (int j = 0; j < 4; ++j) {
                const int r = rg * 16 + lq * 4 + j;
                out[(size_t)(b0 + r) * H + d] = oacc[n][j];
            }
        }
    }
}

// ---------------------------------------------------------------------------
// Fallback (round-2 kernel, proven correct) if ws is too small.
// ---------------------------------------------------------------------------
__global__ __launch_bounds__(256) void moe_fused_fallback(
    const float* __restrict__ x, const float* __restrict__ xr,
    const float* __restrict__ Wr, const float* __restrict__ We,
    const float* __restrict__ be, float* __restrict__ out)
{
    const int b = blockIdx.x;
    const int t = threadIdx.x;

    __shared__ float  pooled[H];
    __shared__ float  xr_s[H];
    __shared__ float4 red4[4][64];
    __shared__ float  logits_s[E];
    __shared__ int    sel[2];
    __shared__ float  wsel[2];

    {
        const float4* xrow = reinterpret_cast<const float4*>(x + (size_t)b * S * H);
        const int c4 = t & 63;
        const int sg = t >> 6;
        float4 acc = make_float4(0.f, 0.f, 0.f, 0.f);
#pragma unroll
        for (int i = 0; i < 16; ++i) {
            float4 v = xrow[(sg + 4 * i) * 64 + c4];
            acc.x += v.x; acc.y += v.y; acc.z += v.z; acc.w += v.w;
        }
        red4[sg][c4] = acc;
        xr_s[t] = xr[(size_t)b * H + t];
    }
    __syncthreads();
    {
        const float* r0 = reinterpret_cast<const float*>(&red4[0][0]);
        const float* r1 = reinterpret_cast<const float*>(&red4[1][0]);
        const float* r2 = reinterpret_cast<const float*>(&red4[2][0]);
        const float* r3 = reinterpret_cast<const float*>(&red4[3][0]);
        pooled[t] = (r0[t] + r1[t] + r2[t] + r3[t]) * (1.0f / (float)S);
    }
    if (t < E) {
        double acc = 0.0;
        for (int h = 0; h < H; ++h)
            acc += (double)xr_s[h] * (double)Wr[h * E + t];
        logits_s[t] = (float)acc;
    }
    __syncthreads();
    if (t == 0) {
        int i0 = 0; float v0 = logits_s[0];
        for (int e = 1; e < E; ++e)
            if (logits_s[e] > v0) { v0 = logits_s[e]; i0 = e; }
        int i1 = -1; float v1 = -3.0e38f;
        for (int e = 0; e < E; ++e) {
            if (e == i0) continue;
            if (logits_s[e] > v1) { v1 = logits_s[e]; i1 = e; }
        }
        const float ex = expf(v1 - v0);
        const float inv = 1.0f / (1.0f + ex);
        sel[0] = i0; sel[1] = i1;
        wsel[0] = inv; wsel[1] = ex * inv;
    }
    __syncthreads();
    {
        const int   e0 = sel[0], e1 = sel[1];
        const float w0 = wsel[0], w1 = wsel[1];
        const float* W0 = We + (size_t)e0 * H * H + t;
        const float* W1 = We + (size_t)e1 * H * H + t;
        float a0 = be[e0 * H + t];
        float a1 = be[e1 * H + t];
#pragma unroll 8
        for (int h = 0; h < H; ++h) {
            const float p = pooled[h];
            a0 = fmaf(p, W0[(size_t)h * H], a0);
            a1 = fmaf(p, W1[(size_t)h * H], a1);
        }
        out[(size_t)b * H + t] = w0 * tanhf(a0) + w1 * tanhf(a1);
    }
}

extern "C" void kernel_launch(void* const* d_in, const int* in_sizes, int n_in,
                              void* d_out, int out_size, void* d_ws, size_t ws_size,
                              hipStream_t stream) {
    const float* x  = (const float*)d_in[0];   // [B,S,H]
    const float* xr = (const float*)d_in[1];   // [B,H]
    const float* Wr = (const float*)d_in[2];   // [H,E]
    const float* We = (const float*)d_in[3];   // [E,H,H]
    const float* be = (const float*)d_in[4];   // [E,H]
    float* out = (float*)d_out;

    (void)in_sizes; (void)n_in; (void)out_size;

    const size_t wf_elems = (size_t)E * H * H;                    // 524288 (1 MiB bf16)
    const size_t need = (wf_elems + (size_t)Bn * H) * sizeof(__hip_bfloat16); // 9 MiB
    if (ws_size >= need) {
        __hip_bfloat16* Wf  = (__hip_bfloat16*)d_ws;
        __hip_bfloat16* pws = Wf + wf_elems;
        prep_wfrag<<<32, 256, 0, stream>>>(We, Wf);
        pool_kernel<<<Bn / 4, 256, 0, stream>>>(x, pws);
        combine_kernel<<<CBLK, TPB, 0, stream>>>(pws, xr, Wr, be, Wf, out);
    } else {
        moe_fused_fallback<<<Bn, 256, 0, stream>>>(x, xr, Wr, We, be, out);
    }
}

// Round 6
// 241.354 us; speedup vs baseline: 1.3656x; 1.1421x over previous
//
#include <hip/hip_runtime.h>
#include <hip/hip_bf16.h>

// Problem constants (match reference)
constexpr int Bn = 16384;
constexpr int S  = 64;
constexpr int H  = 256;
constexpr int E  = 8;

constexpr int RPB  = 32;           // rows per combine block
constexpr int CBLK = Bn / RPB;     // 512 combine blocks
constexpr int PSTR = H + 8;        // 264 bf16 row stride in LDS

constexpr int POOLB = Bn / 4;      // 4096 streaming blocks (4 rows each)
constexpr int PREPB = E * 8;       // 64 prep blocks (8 experts x 8 k-tiles of 32 h)

typedef short bf16x8 __attribute__((ext_vector_type(8)));
typedef float f32x4  __attribute__((ext_vector_type(4)));

__device__ __forceinline__ float fast_tanh(float x) {
    const float ex = __expf(2.0f * x);
    return (ex - 1.0f) / (ex + 1.0f);
}

// ---------------------------------------------------------------------------
// Stage 1 (merged): blocks [0,POOLB) = streaming mean-pool (one wave per row,
// no reduction, nontemporal reads); blocks [POOLB, POOLB+PREPB) = Wf prep
// (runs in tail scheduler slots, hidden under the 1 GB stream).
//
// Wf fragment order: chunk ((e*8+kk)*16 + nt)*64 + lane holds 8 bf16,
// element j = We[e][h = kk*32 + (lane>>4)*8 + j][d = nt*16 + (lane&15)].
// ---------------------------------------------------------------------------
__global__ __launch_bounds__(256) void stage1_kernel(
    const float* __restrict__ x,
    const float* __restrict__ We,
    __hip_bfloat16* __restrict__ pws,
    __hip_bfloat16* __restrict__ Wf)
{
    __shared__ __hip_bfloat16 tile[32][H + 4];   // prep only: [h_local][d], 16.6 KB
    const int t = threadIdx.x;

    if (blockIdx.x < POOLB) {
        // ---- pool: 4 rows per block, one wave per row ----
        const int row = blockIdx.x * 4 + (t >> 6);
        const int c4  = t & 63;

        const f32x4* xrow = reinterpret_cast<const f32x4*>(x + (size_t)row * (S * H));
        f32x4 a0 = 0.f, a1 = 0.f, a2 = 0.f, a3 = 0.f;
#pragma unroll 16
        for (int s = 0; s < S; s += 4) {
            f32x4 v0 = __builtin_nontemporal_load(xrow + (s + 0) * 64 + c4);
            f32x4 v1 = __builtin_nontemporal_load(xrow + (s + 1) * 64 + c4);
            f32x4 v2 = __builtin_nontemporal_load(xrow + (s + 2) * 64 + c4);
            f32x4 v3 = __builtin_nontemporal_load(xrow + (s + 3) * 64 + c4);
            a0 += v0; a1 += v1; a2 += v2; a3 += v3;
        }
        const f32x4 res = (a0 + a1) + (a2 + a3);
        const float sc = 1.0f / (float)S;
        ushort4 pk;
        {
            __hip_bfloat16 h0 = __float2bfloat16(res[0] * sc);
            __hip_bfloat16 h1 = __float2bfloat16(res[1] * sc);
            __hip_bfloat16 h2 = __float2bfloat16(res[2] * sc);
            __hip_bfloat16 h3 = __float2bfloat16(res[3] * sc);
            pk.x = *reinterpret_cast<unsigned short*>(&h0);
            pk.y = *reinterpret_cast<unsigned short*>(&h1);
            pk.z = *reinterpret_cast<unsigned short*>(&h2);
            pk.w = *reinterpret_cast<unsigned short*>(&h3);
        }
        *reinterpret_cast<ushort4*>(pws + (size_t)row * H + c4 * 4) = pk;
    } else {
        // ---- prep: one (expert, k-tile) per block ----
        const int bid = blockIdx.x - POOLB;
        const int e   = bid >> 3;
        const int kk  = bid & 7;          // k-tile = 32 h rows

        const float* src = We + ((size_t)e * H + kk * 32) * H;   // 32 h-rows x 256 d
#pragma unroll
        for (int i = 0; i < 8; ++i) {
            const int idx = t + 256 * i;    // 0..2047
            const int hh  = idx >> 6;       // 0..31
            const int c4  = idx & 63;
            float4 v = reinterpret_cast<const float4*>(src + (size_t)hh * H)[c4];
            tile[hh][c4 * 4 + 0] = __float2bfloat16(v.x);
            tile[hh][c4 * 4 + 1] = __float2bfloat16(v.y);
            tile[hh][c4 * 4 + 2] = __float2bfloat16(v.z);
            tile[hh][c4 * 4 + 3] = __float2bfloat16(v.w);
        }
        __syncthreads();

        // 1024 16B-chunks, 4 per thread, coalesced dwordx4 stores
#pragma unroll
        for (int i = 0; i < 4; ++i) {
            const int task = i * 256 + t;   // 0..1023
            const int nt_  = task >> 6;     // 0..15
            const int l    = task & 63;
            const int hlb  = (l >> 4) * 8;
            const int d    = nt_ * 16 + (l & 15);
            bf16x8 p;
#pragma unroll
            for (int j = 0; j < 8; ++j) {
                __hip_bfloat16 hv = tile[hlb + j][d];
                p[j] = *reinterpret_cast<short*>(&hv);
            }
            reinterpret_cast<bf16x8*>(Wf)[(((size_t)(e * 8 + kk) * 16 + nt_) * 64 + l)] = p;
        }
    }
}

// ---------------------------------------------------------------------------
// Combine: 256 threads / 4 waves. Wave w = dg (column group of 64 d).
// Each wave computes BOTH m-tiles (rows 0-15, 16-31) from ONE B-frag load
// -> Wf traffic halved vs round 5. Routing/gate/MFMA math identical.
// ---------------------------------------------------------------------------
__global__ __launch_bounds__(256, 2) void combine_kernel(
    const __hip_bfloat16* __restrict__ pws,    // [B][H] bf16
    const float* __restrict__ xr,              // [B][H]
    const float* __restrict__ Wr,              // [H][E]
    const float* __restrict__ be,              // [E][H]
    const __hip_bfloat16* __restrict__ Wf,     // fragment-ordered, 1 MiB
    float* __restrict__ out)                   // [B][H] f32
{
    const int b0 = blockIdx.x * RPB;
    const int t  = threadIdx.x;

    __shared__ __hip_bfloat16 pooled[RPB][PSTR];
    __shared__ float logit_s[RPB][E];
    __shared__ float gate_s[RPB][E];

    // ---- stage pooled rows (16 KB, coalesced bf16x8; 64 B per thread) ----
    {
        const __hip_bfloat16* src = pws + (size_t)b0 * H + t * 32;
#pragma unroll
        for (int u = 0; u < 4; ++u) {
            const int g = t * 32 + u * 8;           // element index 0..8191
            bf16x8 v = *reinterpret_cast<const bf16x8*>(src + u * 8);
            *reinterpret_cast<bf16x8*>(&pooled[g >> 8][g & 255]) = v;
        }
    }

    // ---- routing logits, f64 accumulation (proven) — all 256 threads ----
    {
        const int r = t >> 3, e = t & 7;
        const float* xrp = xr + (size_t)(b0 + r) * H;
        double acc = 0.0;
#pragma unroll 8
        for (int h = 0; h < H; ++h)
            acc += (double)xrp[h] * (double)Wr[h * E + e];
        logit_s[r][e] = (float)acc;
    }
    __syncthreads();

    // ---- top-2 + softmax -> dense gate (proven) ----
    if (t < RPB) {
        int i0 = 0; float v0 = logit_s[t][0];
#pragma unroll
        for (int e = 1; e < E; ++e)
            if (logit_s[t][e] > v0) { v0 = logit_s[t][e]; i0 = e; }
        int i1 = -1; float v1 = -3.0e38f;
#pragma unroll
        for (int e = 0; e < E; ++e) {
            if (e == i0) continue;
            if (logit_s[t][e] > v1) { v1 = logit_s[t][e]; i1 = e; }
        }
        const float ex  = expf(v1 - v0);
        const float inv = 1.0f / (1.0f + ex);
#pragma unroll
        for (int e = 0; e < E; ++e) gate_s[t][e] = 0.f;
        gate_s[t][i0] = inv;
        gate_s[t][i1] = ex * inv;
    }
    __syncthreads();

    // ---- dense 8-expert MFMA (2 m-tiles per wave) + tanh + gate combine ----
    {
        const int dg = t >> 6;          // wave = column group: cols dg*64 .. +63
        const int l  = t & 63;
        const int lr = l & 15;
        const int lq = l >> 4;          // quarter 0..3

        f32x4 oacc[2][4];
#pragma unroll
        for (int m = 0; m < 2; ++m)
#pragma unroll
            for (int n = 0; n < 4; ++n) oacc[m][n] = 0.f;

        const __hip_bfloat16* a0base = &pooled[lr][lq * 8];        // m=0: rows 0..15
        const __hip_bfloat16* a1base = &pooled[16 + lr][lq * 8];   // m=1: rows 16..31
        const bf16x8* wf8 = reinterpret_cast<const bf16x8*>(Wf);

        for (int e = 0; e < E; ++e) {
            f32x4 acc[2][4];
#pragma unroll
            for (int m = 0; m < 2; ++m)
#pragma unroll
                for (int n = 0; n < 4; ++n) acc[m][n] = 0.f;

#pragma unroll
            for (int kk = 0; kk < 8; ++kk) {
                const bf16x8 a0 = *reinterpret_cast<const bf16x8*>(a0base + kk * 32);
                const bf16x8 a1 = *reinterpret_cast<const bf16x8*>(a1base + kk * 32);
                const size_t kb = ((size_t)(e * 8 + kk) * 16 + dg * 4) * 64 + l;
                bf16x8 bfr[4];
#pragma unroll
                for (int n = 0; n < 4; ++n)
                    bfr[n] = wf8[kb + (size_t)n * 64];
#pragma unroll
                for (int n = 0; n < 4; ++n) {
                    acc[0][n] = __builtin_amdgcn_mfma_f32_16x16x32_bf16(a0, bfr[n], acc[0][n], 0, 0, 0);
                    acc[1][n] = __builtin_amdgcn_mfma_f32_16x16x32_bf16(a1, bfr[n], acc[1][n], 0, 0, 0);
                }
            }

            float g[2][4];
#pragma unroll
            for (int m = 0; m < 2; ++m)
#pragma unroll
                for (int j = 0; j < 4; ++j)
                    g[m][j] = gate_s[m * 16 + lq * 4 + j][e];
#pragma unroll
            for (int n = 0; n < 4; ++n) {
                const int d = dg * 64 + n * 16 + lr;
                const float bias = be[e * H + d];
#pragma unroll
                for (int m = 0; m < 2; ++m)
#pragma unroll
                    for (int j = 0; j < 4; ++j)
                        oacc[m][n][j] += g[m][j] * fast_tanh(acc[m][n][j] + bias);
            }
        }

        // C/D layout: col = lane&15 (-> d), row = (lane>>4)*4 + j (-> batch row)
#pragma unroll
        for (int m = 0; m < 2; ++m)
#pragma unroll
            for (int n = 0; n < 4; ++n) {
                const int d = dg * 64 + n * 16 + lr;
#pragma unroll
                for (int j = 0; j < 4; ++j) {
                    const int r = m * 16 + lq * 4 + j;
                    out[(size_t)(b0 + r) * H + d] = oacc[m][n][j];
                }
            }
    }
}

// ---------------------------------------------------------------------------
// Fallback (round-2 kernel, proven correct) if ws is too small.
// ---------------------------------------------------------------------------
__global__ __launch_bounds__(256) void moe_fused_fallback(
    const float* __restrict__ x, const float* __restrict__ xr,
    const float* __restrict__ Wr, const float* __restrict__ We,
    const float* __restrict__ be, float* __restrict__ out)
{
    const int b = blockIdx.x;
    const int t = threadIdx.x;

    __shared__ float  pooled[H];
    __shared__ float  xr_s[H];
    __shared__ float4 red4[4][64];
    __shared__ float  logits_s[E];
    __shared__ int    sel[2];
    __shared__ float  wsel[2];

    {
        const float4* xrow = reinterpret_cast<const float4*>(x + (size_t)b * S * H);
        const int c4 = t & 63;
        const int sg = t >> 6;
        float4 acc = make_float4(0.f, 0.f, 0.f, 0.f);
#pragma unroll
        for (int i = 0; i < 16; ++i) {
            float4 v = xrow[(sg + 4 * i) * 64 + c4];
            acc.x += v.x; acc.y += v.y; acc.z += v.z; acc.w += v.w;
        }
        red4[sg][c4] = acc;
        xr_s[t] = xr[(size_t)b * H + t];
    }
    __syncthreads();
    {
        const float* r0 = reinterpret_cast<const float*>(&red4[0][0]);
        const float* r1 = reinterpret_cast<const float*>(&red4[1][0]);
        const float* r2 = reinterpret_cast<const float*>(&red4[2][0]);
        const float* r3 = reinterpret_cast<const float*>(&red4[3][0]);
        pooled[t] = (r0[t] + r1[t] + r2[t] + r3[t]) * (1.0f / (float)S);
    }
    if (t < E) {
        double acc = 0.0;
        for (int h = 0; h < H; ++h)
            acc += (double)xr_s[h] * (double)Wr[h * E + t];
        logits_s[t] = (float)acc;
    }
    __syncthreads();
    if (t == 0) {
        int i0 = 0; float v0 = logits_s[0];
        for (int e = 1; e < E; ++e)
            if (logits_s[e] > v0) { v0 = logits_s[e]; i0 = e; }
        int i1 = -1; float v1 = -3.0e38f;
        for (int e = 0; e < E; ++e) {
            if (e == i0) continue;
            if (logits_s[e] > v1) { v1 = logits_s[e]; i1 = e; }
        }
        const float ex = expf(v1 - v0);
        const float inv = 1.0f / (1.0f + ex);
        sel[0] = i0; sel[1] = i1;
        wsel[0] = inv; wsel[1] = ex * inv;
    }
    __syncthreads();
    {
        const int   e0 = sel[0], e1 = sel[1];
        const float w0 = wsel[0], w1 = wsel[1];
        const float* W0 = We + (size_t)e0 * H * H + t;
        const float* W1 = We + (size_t)e1 * H * H + t;
        float a0 = be[e0 * H + t];
        float a1 = be[e1 * H + t];
#pragma unroll 8
        for (int h = 0; h < H; ++h) {
            const float p = pooled[h];
            a0 = fmaf(p, W0[(size_t)h * H], a0);
            a1 = fmaf(p, W1[(size_t)h * H], a1);
        }
        out[(size_t)b * H + t] = w0 * tanhf(a0) + w1 * tanhf(a1);
    }
}

extern "C" void kernel_launch(void* const* d_in, const int* in_sizes, int n_in,
                              void* d_out, int out_size, void* d_ws, size_t ws_size,
                              hipStream_t stream) {
    const float* x  = (const float*)d_in[0];   // [B,S,H]
    const float* xr = (const float*)d_in[1];   // [B,H]
    const float* Wr = (const float*)d_in[2];   // [H,E]
    const float* We = (const float*)d_in[3];   // [E,H,H]
    const float* be = (const float*)d_in[4];   // [E,H]
    float* out = (float*)d_out;

    (void)in_sizes; (void)n_in; (void)out_size;

    const size_t wf_elems = (size_t)E * H * H;                    // 524288 (1 MiB bf16)
    const size_t need = (wf_elems + (size_t)Bn * H) * sizeof(__hip_bfloat16); // 9 MiB
    if (ws_size >= need) {
        __hip_bfloat16* Wf  = (__hip_bfloat16*)d_ws;
        __hip_bfloat16* pws = Wf + wf_elems;
        stage1_kernel<<<POOLB + PREPB, 256, 0, stream>>>(x, We, pws, Wf);
        combine_kernel<<<CBLK, 256, 0, stream>>>(pws, xr, Wr, be, Wf, out);
    } else {
        moe_fused_fallback<<<Bn, 256, 0, stream>>>(x, xr, Wr, We, be, out);
    }
}